// Round 10
// baseline (465.336 us; speedup 1.0000x reference)
//
#include <hip/hip_runtime.h>
#include <hip/hip_bf16.h>

#define F_IN 256
#define HID  64
#define CLS  40
#define EPS  1e-8f
#define NSEG 8          // XCD count: blockIdx % 8 -> XCD (locality heuristic)
#define XS_STRIDE 264   // halfwords per LDS x-tile row: 2-way max bank aliasing (free)

typedef unsigned short ushort_t;
typedef unsigned int   uint_t;
typedef __attribute__((ext_vector_type(8))) short bf16x8;
typedef __attribute__((ext_vector_type(4))) float f32x4;
typedef __attribute__((ext_vector_type(4))) float fv4;   // clang vector: ok for nontemporal builtins

__device__ __forceinline__ float bf2f(ushort_t u) {
    union { uint_t i; float f; } v; v.i = ((uint_t)u) << 16; return v.f;
}
__device__ __forceinline__ ushort_t f2bf(float f) {
    union { float f; uint_t i; } v; v.f = f;
    uint_t r = v.i + 0x7fff + ((v.i >> 16) & 1);          // RNE
    return (ushort_t)(r >> 16);
}
__device__ __forceinline__ float blo(uint_t p) {
    union { uint_t i; float f; } v; v.i = p << 16; return v.f;
}
__device__ __forceinline__ float bhi(uint_t p) {
    union { uint_t i; float f; } v; v.i = p & 0xffff0000u; return v.f;
}
__device__ __forceinline__ float dot_u4(uint4 a, uint4 b) {
    return blo(a.x) * blo(b.x) + bhi(a.x) * bhi(b.x)
         + blo(a.y) * blo(b.y) + bhi(a.y) * bhi(b.y)
         + blo(a.z) * blo(b.z) + bhi(a.z) * bhi(b.z)
         + blo(a.w) * blo(b.w) + bhi(a.w) * bhi(b.w);
}

// -------------------- dtype detection (int64 vs int32 edge_index) -----------
__global__ void detect_kernel(const int* __restrict__ raw, int* __restrict__ flag) {
    int c = threadIdx.x;                  // one wave
    int w = raw[2 * c + 1];               // odd int32 words
    unsigned long long b = __ballot(w != 0);
    if (c == 0) *flag = (b == 0ULL) ? 1 : 0;   // all zero -> int64 layout
}

__global__ void init_deg_kernel(int* __restrict__ deg, int n) {
    int v = blockIdx.x * blockDim.x + threadIdx.x;
    if (v < n) deg[v] = 1;                // self-loop
}

// ---- convert: pack (dst<<16)|src into one uint + direct atomic degree ------
// streaming reads/writes marked non-temporal (keep L2 clean for atomics)
__global__ void convert_kernel(const void* __restrict__ raw, const int* __restrict__ flag,
                               uint_t* __restrict__ pair, int* __restrict__ deg, int E) {
    int e = blockIdx.x * blockDim.x + threadIdx.x;
    if (e >= E) return;
    uint_t s, d;
    if (*flag) {
        const long long* r = (const long long*)raw;
        s = (uint_t)__builtin_nontemporal_load(r + e);
        d = (uint_t)__builtin_nontemporal_load(r + E + e);
    } else {
        const int* r = (const int*)raw;
        s = (uint_t)__builtin_nontemporal_load(r + e);
        d = (uint_t)__builtin_nontemporal_load(r + E + e);
    }
    __builtin_nontemporal_store((d << 16) | s, pair + e);
    atomicAdd(&deg[d], 1);
}

// ---- W1 -> bf16, pre-swizzled into MFMA B-fragment order -------------------
// frag elem j of (nt, kk, lane): W1[kk*32 + (lane>>4)*8 + j][nt*16 + (lane&15)]
// stored contiguously at W1s[(((nt*8)+kk)*64 + lane)*8 + j]
__global__ void convert_w1_kernel(const float* __restrict__ W1, ushort_t* __restrict__ W1s) {
    int t = blockIdx.x * blockDim.x + threadIdx.x;   // 2048 triples
    if (t >= 4 * 8 * 64) return;
    int lane = t & 63;
    int kk   = (t >> 6) & 7;
    int nt   = t >> 9;
    int col  = nt * 16 + (lane & 15);
    int k0   = kk * 32 + (lane >> 4) * 8;
    ushort_t v[8];
    #pragma unroll
    for (int j = 0; j < 8; ++j) v[j] = f2bf(W1[(size_t)(k0 + j) * HID + col]);
    uint4 p;
    p.x = (uint_t)v[0] | ((uint_t)v[1] << 16);
    p.y = (uint_t)v[2] | ((uint_t)v[3] << 16);
    p.z = (uint_t)v[4] | ((uint_t)v[5] << 16);
    p.w = (uint_t)v[6] | ((uint_t)v[7] << 16);
    *(uint4*)(W1s + (size_t)t * 8) = p;
}

// ---------- multi-block exclusive scan of (deg[i]-1) -> rowptr/cursor -------
// phase 1: block-local exclusive scan, block totals to bsum; also dinv
__global__ void scan1_kernel(const int* __restrict__ deg, int* __restrict__ rowptr,
                             int* __restrict__ bsum, float* __restrict__ dinv, int n) {
    __shared__ int s[256];
    int tid = threadIdx.x;
    int i = blockIdx.x * 256 + tid;
    int dg = (i < n) ? deg[i] : 1;
    if (i < n) dinv[i] = rsqrtf((float)dg);        // deg >= 1 always
    int v = dg - 1;
    int x = v;
    s[tid] = x;
    __syncthreads();
    #pragma unroll
    for (int o = 1; o < 256; o <<= 1) {
        int t = (tid >= o) ? s[tid - o] : 0;
        __syncthreads();
        x += t;
        s[tid] = x;
        __syncthreads();
    }
    if (i < n) rowptr[i] = x - v;                  // block-local exclusive
    if (tid == 255) bsum[blockIdx.x] = x;          // block total
}

// phase 2: exclusive scan of block sums (nb <= 256), single block
__global__ void scan2_kernel(int* __restrict__ bsum, int nb) {
    __shared__ int s[256];
    int tid = threadIdx.x;
    int v = (tid < nb) ? bsum[tid] : 0;
    int x = v;
    s[tid] = x;
    __syncthreads();
    #pragma unroll
    for (int o = 1; o < 256; o <<= 1) {
        int t = (tid >= o) ? s[tid - o] : 0;
        __syncthreads();
        x += t;
        s[tid] = x;
        __syncthreads();
    }
    if (tid < nb) bsum[tid] = x - v;               // exclusive block offsets
}

// phase 3: add block offsets; write cursor; rowptr[n] = E
__global__ void scan3_kernel(int* __restrict__ rowptr, int* __restrict__ cursor,
                             const int* __restrict__ bsum, int n, int E) {
    int i = blockIdx.x * 256 + threadIdx.x;
    if (i < n) {
        int r = rowptr[i] + bsum[blockIdx.x];
        rowptr[i] = r;
        cursor[i] = r;
    }
    if (i == 0) rowptr[n] = E;                     // sum(deg-1) == E
}

// ---- binned fill: only XCD group p writes csr/cursor slice p ---------------
// pair stream read non-temporally so dirty csr/cursor lines stay in L2
__global__ void fill_binned_kernel(const uint_t* __restrict__ pair,
                                   int* __restrict__ cursor, ushort_t* __restrict__ csr,
                                   int E, int n) {
    int p      = blockIdx.x & (NSEG - 1);
    int chunk  = blockIdx.x / NSEG;
    int nchunk = gridDim.x / NSEG;
    int lo = (p * n) / NSEG;
    int hi = ((p + 1) * n) / NSEG;
    int ce = (E + nchunk - 1) / nchunk;
    int e0 = chunk * ce;
    int e1 = min(e0 + ce, E);
    for (int e = e0 + threadIdx.x; e < e1; e += blockDim.x) {
        uint_t u = __builtin_nontemporal_load(pair + e);
        int d = (int)(u >> 16);
        if (d >= lo && d < hi) {
            int pos = atomicAdd(&cursor[d], 1);
            csr[pos] = (ushort_t)(u & 0xffffu);
        }
    }
}

// ------- layer 1 GEMM on MFMA: xws = bf16((x @ W1) * dinv[node]) ------------
// block = 256 threads = 4 waves; 16 nodes/block; wave w owns N-tile w (16 ch)
__global__ void gemm1_mfma_kernel(const float* __restrict__ x,
                                  const ushort_t* __restrict__ W1s,
                                  const float* __restrict__ dinv,
                                  ushort_t* __restrict__ xws, int n) {
    __shared__ ushort_t xs[16 * XS_STRIDE];           // 8448 B bf16 x-tile
    int node0 = blockIdx.x * 16;
    int tid = threadIdx.x;
    for (int i = tid; i < 16 * 64; i += 256) {        // stage x tile -> bf16 LDS
        int r  = i >> 6;
        int c4 = (i & 63) << 2;
        int node = node0 + r;
        fv4 v = {0.f, 0.f, 0.f, 0.f};
        if (node < n)
            v = __builtin_nontemporal_load((const fv4*)(x + (size_t)node * F_IN + c4));
        ushort4 b;
        b.x = f2bf(v.x); b.y = f2bf(v.y); b.z = f2bf(v.z); b.w = f2bf(v.w);
        *(ushort4*)(&xs[r * XS_STRIDE + c4]) = b;     // 8B-aligned ds_write_b64
    }
    __syncthreads();
    int wave = tid >> 6;                              // N-tile index 0..3
    int lane = tid & 63;
    int m    = lane & 15;
    int q    = lane >> 4;
    f32x4 acc = {0.f, 0.f, 0.f, 0.f};
    #pragma unroll
    for (int kk = 0; kk < 8; ++kk) {                  // K = 8 x 32
        bf16x8 a = *(const bf16x8*)(&xs[m * XS_STRIDE + kk * 32 + q * 8]);
        bf16x8 b = *(const bf16x8*)(W1s + (((size_t)wave * 8 + kk) * 64 + lane) * 8);
        acc = __builtin_amdgcn_mfma_f32_16x16x32_bf16(a, b, acc, 0, 0, 0);
    }
    int ch = wave * 16 + m;                           // C/D: col=lane&15, row=q*4+r
    #pragma unroll
    for (int r = 0; r < 4; ++r) {
        int node = node0 + q * 4 + r;
        if (node < n)
            xws[(size_t)node * HID + ch] = f2bf(acc[r] * dinv[node]);
    }
}

// ---- fused: gather1 (h = relu(dinv*(sum)+b1)) + gemm2 (hws = h@W2 * dinv) --
// one wave per node; 4 waves/block; h row staged in LDS for the 64->40 matmul
// csr read non-temporally (read-once stream; keep xws table hot in L2)
__global__ void gather1_gemm2_kernel(const int* __restrict__ rowptr,
                                     const ushort_t* __restrict__ csr,
                                     const ushort_t* __restrict__ xws,
                                     const float* __restrict__ dinv,
                                     const float* __restrict__ b1,
                                     const float* __restrict__ W2,
                                     ushort_t* __restrict__ hws, int n) {
    __shared__ float hbuf[4][72];
    int wave = threadIdx.x >> 6;
    int c    = threadIdx.x & 63;
    int wv   = (blockIdx.x * blockDim.x + threadIdx.x) >> 6;
    bool active = wv < n;
    int beg = 0, endp = 0;
    float acc = 0.f, di = 0.f;
    if (active) {
        beg = rowptr[wv]; endp = rowptr[wv + 1];
        di  = dinv[wv];
        acc = bf2f(xws[(size_t)wv * HID + c]);        // self-loop term
    }
    int j = beg;
    for (; j + 8 <= endp; j += 8) {                   // 8 outstanding row loads
        int s0 = __builtin_nontemporal_load(csr + j);
        int s1 = __builtin_nontemporal_load(csr + j + 1);
        int s2 = __builtin_nontemporal_load(csr + j + 2);
        int s3 = __builtin_nontemporal_load(csr + j + 3);
        int s4 = __builtin_nontemporal_load(csr + j + 4);
        int s5 = __builtin_nontemporal_load(csr + j + 5);
        int s6 = __builtin_nontemporal_load(csr + j + 6);
        int s7 = __builtin_nontemporal_load(csr + j + 7);
        float v0 = bf2f(xws[(size_t)s0 * HID + c]);
        float v1 = bf2f(xws[(size_t)s1 * HID + c]);
        float v2 = bf2f(xws[(size_t)s2 * HID + c]);
        float v3 = bf2f(xws[(size_t)s3 * HID + c]);
        float v4 = bf2f(xws[(size_t)s4 * HID + c]);
        float v5 = bf2f(xws[(size_t)s5 * HID + c]);
        float v6 = bf2f(xws[(size_t)s6 * HID + c]);
        float v7 = bf2f(xws[(size_t)s7 * HID + c]);
        acc += ((v0 + v1) + (v2 + v3)) + ((v4 + v5) + (v6 + v7));
    }
    for (; j < endp; ++j) acc += bf2f(xws[(size_t)csr[j] * HID + c]);
    float hv = active ? fmaxf(acc * di + b1[c], 0.f) : 0.f;
    hbuf[wave][c] = hv;
    __syncthreads();
    if (active && c < CLS) {
        float o = 0.f;
        const float* hr = hbuf[wave];
        #pragma unroll 8
        for (int k = 0; k < HID; ++k) o += hr[k] * W2[k * CLS + c];
        hws[(size_t)wv * CLS + c] = f2bf(o * di);
    }
}

// ---------- layer 2 gather fused with finalize ------------------------------
__global__ void gather2_fin_kernel(const int* __restrict__ rowptr,
                                   const ushort_t* __restrict__ csr,
                                   const ushort_t* __restrict__ hws,
                                   const float* __restrict__ dinv,
                                   const float* __restrict__ b2,
                                   float* __restrict__ xout, float* __restrict__ lsm,
                                   float* __restrict__ sm, ushort_t* __restrict__ xoutb,
                                   float* __restrict__ rnorm, int n) {
    int wv = (blockIdx.x * blockDim.x + threadIdx.x) >> 6;
    int c  = threadIdx.x & 63;
    if (wv >= n) return;
    int beg = rowptr[wv], endp = rowptr[wv + 1];
    bool act = c < CLS;
    float acc = 0.f;
    if (act) acc = bf2f(hws[(size_t)wv * CLS + c]);   // self-loop term
    int j = beg;
    for (; j + 8 <= endp; j += 8) {
        int s0 = __builtin_nontemporal_load(csr + j);
        int s1 = __builtin_nontemporal_load(csr + j + 1);
        int s2 = __builtin_nontemporal_load(csr + j + 2);
        int s3 = __builtin_nontemporal_load(csr + j + 3);
        int s4 = __builtin_nontemporal_load(csr + j + 4);
        int s5 = __builtin_nontemporal_load(csr + j + 5);
        int s6 = __builtin_nontemporal_load(csr + j + 6);
        int s7 = __builtin_nontemporal_load(csr + j + 7);
        if (act) {
            float v0 = bf2f(hws[(size_t)s0 * CLS + c]);
            float v1 = bf2f(hws[(size_t)s1 * CLS + c]);
            float v2 = bf2f(hws[(size_t)s2 * CLS + c]);
            float v3 = bf2f(hws[(size_t)s3 * CLS + c]);
            float v4 = bf2f(hws[(size_t)s4 * CLS + c]);
            float v5 = bf2f(hws[(size_t)s5 * CLS + c]);
            float v6 = bf2f(hws[(size_t)s6 * CLS + c]);
            float v7 = bf2f(hws[(size_t)s7 * CLS + c]);
            acc += ((v0 + v1) + (v2 + v3)) + ((v4 + v5) + (v6 + v7));
        }
    }
    for (; j < endp; ++j) {
        int s = csr[j];
        if (act) acc += bf2f(hws[(size_t)s * CLS + c]);
    }
    float raw = 0.f;
    if (act) raw = acc * dinv[wv] + b2[c];
    float m = act ? raw : -3.0e38f;
    #pragma unroll
    for (int o = 32; o > 0; o >>= 1) m = fmaxf(m, __shfl_xor(m, o));
    float ex = act ? __expf(raw - m) : 0.f;
    float ssum = ex;
    #pragma unroll
    for (int o = 32; o > 0; o >>= 1) ssum += __shfl_xor(ssum, o);
    float sq = act ? raw * raw : 0.f;
    #pragma unroll
    for (int o = 32; o > 0; o >>= 1) sq += __shfl_xor(sq, o);
    size_t base = (size_t)wv * CLS + c;
    if (act) {
        __builtin_nontemporal_store(raw, xout + base);
        float lse = m + __logf(ssum);
        __builtin_nontemporal_store(raw - lse, lsm + base);
        __builtin_nontemporal_store(ex / ssum, sm + base);
        xoutb[base] = f2bf(raw);                      // cached: edge_kernel re-reads
    }
    if (c == 0) rnorm[wv] = 1.0f / fmaxf(sqrtf(sq), EPS);
}

// ------------- per-edge cosine dissimilarity + gnn_edge ---------------------
// 80B row = 5 x uint4 loads per operand (full 40 bf16 channels)
// pair/ew streamed non-temporally; outputs nt stores; xoutb stays cached
__global__ void edge_kernel(const uint_t* __restrict__ pair,
                            const float* __restrict__ ew, const ushort_t* __restrict__ xoutb,
                            const float* __restrict__ rnorm,
                            float* __restrict__ cos_out, float* __restrict__ gnn_out, int E) {
    int e = blockIdx.x * blockDim.x + threadIdx.x;
    if (e >= E) return;
    uint_t u = __builtin_nontemporal_load(pair + e);
    int s = (int)(u & 0xffffu);
    int d = (int)(u >> 16);
    const uint4* a4 = (const uint4*)(xoutb + (size_t)s * CLS);   // rows are 80B = 5*16B
    const uint4* b4 = (const uint4*)(xoutb + (size_t)d * CLS);
    uint4 a0 = a4[0], a1 = a4[1], a2 = a4[2], a3 = a4[3], a4v = a4[4];
    uint4 b0 = b4[0], b1 = b4[1], b2 = b4[2], b3 = b4[3], b4v = b4[4];
    float rs = rnorm[s], rd = rnorm[d];
    float dot = dot_u4(a0, b0) + dot_u4(a1, b1) + dot_u4(a2, b2)
              + dot_u4(a3, b3) + dot_u4(a4v, b4v);
    float ewv = __builtin_nontemporal_load(ew + e);
    __builtin_nontemporal_store(1.0f - dot * rs * rd, cos_out + e);
    __builtin_nontemporal_store((ewv > 0.5f) ? 1.0f : -1.0f, gnn_out + e);
}

// ---------------------------------------------------------------------------
extern "C" void kernel_launch(void* const* d_in, const int* in_sizes, int n_in,
                              void* d_out, int out_size, void* d_ws, size_t ws_size,
                              hipStream_t stream) {
    const float* x   = (const float*)d_in[0];
    const void*  ei  = d_in[1];
    const float* ew  = (const float*)d_in[2];
    const float* W1  = (const float*)d_in[3];
    const float* b1  = (const float*)d_in[4];
    const float* W2  = (const float*)d_in[5];
    const float* b2  = (const float*)d_in[6];

    const int n = in_sizes[0] / F_IN;        // 50000
    const int E = in_sizes[2];               // 1600000

    // output segments (return order)
    float* lsm  = (float*)d_out;                                   // [n*CLS]
    float* xout = lsm + (size_t)n * CLS;                           // [n*CLS]
    float* cosO = xout + (size_t)n * CLS;                          // [E]
    float* gnnO = cosO + E;                                        // [E]
    float* smO  = gnnO + E;                                        // [n*CLS]

    // workspace layout (256B aligned)
    char* w = (char*)d_ws;
    auto alloc = [&](size_t bytes) {
        char* p = w;
        w += (bytes + 255) & ~(size_t)255;
        return p;
    };
    uint_t*   pair   = (uint_t*)  alloc((size_t)E * 4);
    ushort_t* csr16  = (ushort_t*)alloc((size_t)E * 2);
    int*      deg    = (int*)     alloc((size_t)n * 4);
    int*      rowptr = (int*)     alloc(((size_t)n + 1) * 4);
    int*      cursor = (int*)     alloc((size_t)n * 4);
    float*    dinv   = (float*)   alloc((size_t)n * 4);
    ushort_t* xws    = (ushort_t*)alloc((size_t)n * HID * 2);
    ushort_t* hws    = (ushort_t*)alloc((size_t)n * CLS * 2);
    ushort_t* xoutb  = (ushort_t*)alloc((size_t)n * CLS * 2);
    float*    rnorm  = (float*)   alloc((size_t)n * 4);
    ushort_t* W1s    = (ushort_t*)alloc((size_t)4 * 8 * 64 * 8 * 2);   // 32 KB
    int*      bsum   = (int*)     alloc(256 * 4);
    int*      flag   = (int*)     alloc(64);

    const int nscan = (n + 255) / 256;       // 196 scan blocks (<= 256)

    detect_kernel<<<1, 64, 0, stream>>>((const int*)ei, flag);
    convert_w1_kernel<<<8, 256, 0, stream>>>(W1, W1s);
    init_deg_kernel<<<(n + 255) / 256, 256, 0, stream>>>(deg, n);
    convert_kernel<<<(E + 255) / 256, 256, 0, stream>>>(ei, flag, pair, deg, E);
    scan1_kernel<<<nscan, 256, 0, stream>>>(deg, rowptr, bsum, dinv, n);
    scan2_kernel<<<1, 256, 0, stream>>>(bsum, nscan);
    scan3_kernel<<<nscan, 256, 0, stream>>>(rowptr, cursor, bsum, n, E);
    fill_binned_kernel<<<128 * NSEG, 256, 0, stream>>>(pair, cursor, csr16, E, n);
    gemm1_mfma_kernel<<<(n + 15) / 16, 256, 0, stream>>>(x, W1s, dinv, xws, n);
    gather1_gemm2_kernel<<<((size_t)n * 64 + 255) / 256, 256, 0, stream>>>(rowptr, csr16, xws, dinv,
                                                                           b1, W2, hws, n);
    gather2_fin_kernel<<<((size_t)n * 64 + 255) / 256, 256, 0, stream>>>(rowptr, csr16, hws, dinv, b2,
                                                                         xout, lsm, smO, xoutb, rnorm, n);
    edge_kernel<<<(E + 255) / 256, 256, 0, stream>>>(pair, ew, xoutb, rnorm, cosO, gnnO, E);
}

// Round 11
// 395.162 us; speedup vs baseline: 1.1776x; 1.1776x over previous
//
#include <hip/hip_runtime.h>
#include <hip/hip_bf16.h>

#define F_IN 256
#define HID  64
#define CLS  40
#define EPS  1e-8f
#define XS_STRIDE 264   // halfwords per LDS x-tile row: 2-way max bank aliasing (free)

typedef unsigned short ushort_t;
typedef unsigned int   uint_t;
typedef __attribute__((ext_vector_type(8))) short bf16x8;
typedef __attribute__((ext_vector_type(4))) float f32x4;

__device__ __forceinline__ float bf2f(ushort_t u) {
    union { uint_t i; float f; } v; v.i = ((uint_t)u) << 16; return v.f;
}
__device__ __forceinline__ ushort_t f2bf(float f) {
    union { float f; uint_t i; } v; v.f = f;
    uint_t r = v.i + 0x7fff + ((v.i >> 16) & 1);          // RNE
    return (ushort_t)(r >> 16);
}
__device__ __forceinline__ float blo(uint_t p) {
    union { uint_t i; float f; } v; v.i = p << 16; return v.f;
}
__device__ __forceinline__ float bhi(uint_t p) {
    union { uint_t i; float f; } v; v.i = p & 0xffff0000u; return v.f;
}
__device__ __forceinline__ float dot_u4(uint4 a, uint4 b) {
    return blo(a.x) * blo(b.x) + bhi(a.x) * bhi(b.x)
         + blo(a.y) * blo(b.y) + bhi(a.y) * bhi(b.y)
         + blo(a.z) * blo(b.z) + bhi(a.z) * bhi(b.z)
         + blo(a.w) * blo(b.w) + bhi(a.w) * bhi(b.w);
}

// -------------------- dtype detection (int64 vs int32 edge_index) -----------
__global__ void detect_kernel(const int* __restrict__ raw, int* __restrict__ flag) {
    int c = threadIdx.x;                  // one wave
    int w = raw[2 * c + 1];               // odd int32 words
    unsigned long long b = __ballot(w != 0);
    if (c == 0) *flag = (b == 0ULL) ? 1 : 0;   // all zero -> int64 layout
}

__global__ void init_deg_kernel(int* __restrict__ deg, int n) {
    int v = blockIdx.x * blockDim.x + threadIdx.x;
    if (v < n) deg[v] = 0;                // edge count only; self-loop added later
}

// ---- convert: pack (dst<<16)|src + degree atomic whose RETURN is the edge's
// rank among same-dst edges -> later CSR placement needs no second atomic pass
__global__ void convert_kernel(const void* __restrict__ raw, const int* __restrict__ flag,
                               uint_t* __restrict__ pair, int* __restrict__ deg,
                               ushort_t* __restrict__ rank16, int E) {
    int e = blockIdx.x * blockDim.x + threadIdx.x;
    if (e >= E) return;
    uint_t s, d;
    if (*flag) {
        const long long* r = (const long long*)raw;
        s = (uint_t)r[e]; d = (uint_t)r[E + e];
    } else {
        const int* r = (const int*)raw;
        s = (uint_t)r[e]; d = (uint_t)r[E + e];
    }
    pair[e] = (d << 16) | s;
    int r = atomicAdd(&deg[d], 1);        // old value = unique rank within dst d
    rank16[e] = (ushort_t)r;              // max deg ~ O(100) << 65536
}

// ---- W1 -> bf16, pre-swizzled into MFMA B-fragment order -------------------
// frag elem j of (nt, kk, lane): W1[kk*32 + (lane>>4)*8 + j][nt*16 + (lane&15)]
// stored contiguously at W1s[(((nt*8)+kk)*64 + lane)*8 + j]
__global__ void convert_w1_kernel(const float* __restrict__ W1, ushort_t* __restrict__ W1s) {
    int t = blockIdx.x * blockDim.x + threadIdx.x;   // 2048 triples
    if (t >= 4 * 8 * 64) return;
    int lane = t & 63;
    int kk   = (t >> 6) & 7;
    int nt   = t >> 9;
    int col  = nt * 16 + (lane & 15);
    int k0   = kk * 32 + (lane >> 4) * 8;
    ushort_t v[8];
    #pragma unroll
    for (int j = 0; j < 8; ++j) v[j] = f2bf(W1[(size_t)(k0 + j) * HID + col]);
    uint4 p;
    p.x = (uint_t)v[0] | ((uint_t)v[1] << 16);
    p.y = (uint_t)v[2] | ((uint_t)v[3] << 16);
    p.z = (uint_t)v[4] | ((uint_t)v[5] << 16);
    p.w = (uint_t)v[6] | ((uint_t)v[7] << 16);
    *(uint4*)(W1s + (size_t)t * 8) = p;
}

// ---------- multi-block exclusive scan of edge-counts -> rowptr -------------
// phase 1: block-local exclusive scan, block totals to bsum; also dinv
__global__ void scan1_kernel(const int* __restrict__ deg, int* __restrict__ rowptr,
                             int* __restrict__ bsum, float* __restrict__ dinv, int n) {
    __shared__ int s[256];
    int tid = threadIdx.x;
    int i = blockIdx.x * 256 + tid;
    int v = (i < n) ? deg[i] : 0;                  // edge count (no self-loop)
    if (i < n) dinv[i] = rsqrtf((float)(v + 1));   // +1 self-loop
    int x = v;
    s[tid] = x;
    __syncthreads();
    #pragma unroll
    for (int o = 1; o < 256; o <<= 1) {
        int t = (tid >= o) ? s[tid - o] : 0;
        __syncthreads();
        x += t;
        s[tid] = x;
        __syncthreads();
    }
    if (i < n) rowptr[i] = x - v;                  // block-local exclusive
    if (tid == 255) bsum[blockIdx.x] = x;          // block total
}

// phase 2: exclusive scan of block sums (nb <= 256), single block
__global__ void scan2_kernel(int* __restrict__ bsum, int nb) {
    __shared__ int s[256];
    int tid = threadIdx.x;
    int v = (tid < nb) ? bsum[tid] : 0;
    int x = v;
    s[tid] = x;
    __syncthreads();
    #pragma unroll
    for (int o = 1; o < 256; o <<= 1) {
        int t = (tid >= o) ? s[tid - o] : 0;
        __syncthreads();
        x += t;
        s[tid] = x;
        __syncthreads();
    }
    if (tid < nb) bsum[tid] = x - v;               // exclusive block offsets
}

// phase 3: add block offsets; rowptr[n] = E
__global__ void scan3_kernel(int* __restrict__ rowptr, const int* __restrict__ bsum,
                             int n, int E) {
    int i = blockIdx.x * 256 + threadIdx.x;
    if (i < n) rowptr[i] += bsum[blockIdx.x];
    if (i == 0) rowptr[n] = E;                     // sum of edge counts == E
}

// ---- place: csr[rowptr[dst] + rank] = src — pure stores, no atomics --------
__global__ void place_kernel(const uint_t* __restrict__ pair,
                             const ushort_t* __restrict__ rank16,
                             const int* __restrict__ rowptr,
                             ushort_t* __restrict__ csr, int E) {
    int e = blockIdx.x * blockDim.x + threadIdx.x;
    if (e >= E) return;
    uint_t u = pair[e];
    int d = (int)(u >> 16);
    int pos = rowptr[d] + (int)rank16[e];
    csr[pos] = (ushort_t)(u & 0xffffu);
}

// ------- layer 1 GEMM on MFMA: xws = bf16((x @ W1) * dinv[node]) ------------
// block = 256 threads = 4 waves; 16 nodes/block; wave w owns N-tile w (16 ch)
__global__ void gemm1_mfma_kernel(const float* __restrict__ x,
                                  const ushort_t* __restrict__ W1s,
                                  const float* __restrict__ dinv,
                                  ushort_t* __restrict__ xws, int n) {
    __shared__ ushort_t xs[16 * XS_STRIDE];           // 8448 B bf16 x-tile
    int node0 = blockIdx.x * 16;
    int tid = threadIdx.x;
    for (int i = tid; i < 16 * 64; i += 256) {        // stage x tile -> bf16 LDS
        int r  = i >> 6;
        int c4 = (i & 63) << 2;
        int node = node0 + r;
        float4 v = (node < n) ? *(const float4*)(x + (size_t)node * F_IN + c4)
                              : make_float4(0.f, 0.f, 0.f, 0.f);
        ushort4 b;
        b.x = f2bf(v.x); b.y = f2bf(v.y); b.z = f2bf(v.z); b.w = f2bf(v.w);
        *(ushort4*)(&xs[r * XS_STRIDE + c4]) = b;     // 8B-aligned ds_write_b64
    }
    __syncthreads();
    int wave = tid >> 6;                              // N-tile index 0..3
    int lane = tid & 63;
    int m    = lane & 15;
    int q    = lane >> 4;
    f32x4 acc = {0.f, 0.f, 0.f, 0.f};
    #pragma unroll
    for (int kk = 0; kk < 8; ++kk) {                  // K = 8 x 32
        bf16x8 a = *(const bf16x8*)(&xs[m * XS_STRIDE + kk * 32 + q * 8]);
        bf16x8 b = *(const bf16x8*)(W1s + (((size_t)wave * 8 + kk) * 64 + lane) * 8);
        acc = __builtin_amdgcn_mfma_f32_16x16x32_bf16(a, b, acc, 0, 0, 0);
    }
    int ch = wave * 16 + m;                           // C/D: col=lane&15, row=q*4+r
    #pragma unroll
    for (int r = 0; r < 4; ++r) {
        int node = node0 + q * 4 + r;
        if (node < n)
            xws[(size_t)node * HID + ch] = f2bf(acc[r] * dinv[node]);
    }
}

// ---- fused: gather1 (h = relu(dinv*(sum)+b1)) + gemm2 (hws = h@W2 * dinv) --
// one wave per node; 4 waves/block; h row staged in LDS for the 64->40 matmul
__global__ void gather1_gemm2_kernel(const int* __restrict__ rowptr,
                                     const ushort_t* __restrict__ csr,
                                     const ushort_t* __restrict__ xws,
                                     const float* __restrict__ dinv,
                                     const float* __restrict__ b1,
                                     const float* __restrict__ W2,
                                     ushort_t* __restrict__ hws, int n) {
    __shared__ float hbuf[4][72];
    int wave = threadIdx.x >> 6;
    int c    = threadIdx.x & 63;
    int wv   = (blockIdx.x * blockDim.x + threadIdx.x) >> 6;
    bool active = wv < n;
    int beg = 0, endp = 0;
    float acc = 0.f, di = 0.f;
    if (active) {
        beg = rowptr[wv]; endp = rowptr[wv + 1];
        di  = dinv[wv];
        acc = bf2f(xws[(size_t)wv * HID + c]);        // self-loop term
    }
    int j = beg;
    for (; j + 8 <= endp; j += 8) {                   // 8 outstanding row loads
        int s0 = csr[j],     s1 = csr[j + 1], s2 = csr[j + 2], s3 = csr[j + 3];
        int s4 = csr[j + 4], s5 = csr[j + 5], s6 = csr[j + 6], s7 = csr[j + 7];
        float v0 = bf2f(xws[(size_t)s0 * HID + c]);
        float v1 = bf2f(xws[(size_t)s1 * HID + c]);
        float v2 = bf2f(xws[(size_t)s2 * HID + c]);
        float v3 = bf2f(xws[(size_t)s3 * HID + c]);
        float v4 = bf2f(xws[(size_t)s4 * HID + c]);
        float v5 = bf2f(xws[(size_t)s5 * HID + c]);
        float v6 = bf2f(xws[(size_t)s6 * HID + c]);
        float v7 = bf2f(xws[(size_t)s7 * HID + c]);
        acc += ((v0 + v1) + (v2 + v3)) + ((v4 + v5) + (v6 + v7));
    }
    for (; j < endp; ++j) acc += bf2f(xws[(size_t)csr[j] * HID + c]);
    float hv = active ? fmaxf(acc * di + b1[c], 0.f) : 0.f;
    hbuf[wave][c] = hv;
    __syncthreads();
    if (active && c < CLS) {
        float o = 0.f;
        const float* hr = hbuf[wave];
        #pragma unroll 8
        for (int k = 0; k < HID; ++k) o += hr[k] * W2[k * CLS + c];
        hws[(size_t)wv * CLS + c] = f2bf(o * di);
    }
}

// ---------- layer 2 gather fused with finalize ------------------------------
__global__ void gather2_fin_kernel(const int* __restrict__ rowptr,
                                   const ushort_t* __restrict__ csr,
                                   const ushort_t* __restrict__ hws,
                                   const float* __restrict__ dinv,
                                   const float* __restrict__ b2,
                                   float* __restrict__ xout, float* __restrict__ lsm,
                                   float* __restrict__ sm, ushort_t* __restrict__ xoutb,
                                   float* __restrict__ rnorm, int n) {
    int wv = (blockIdx.x * blockDim.x + threadIdx.x) >> 6;
    int c  = threadIdx.x & 63;
    if (wv >= n) return;
    int beg = rowptr[wv], endp = rowptr[wv + 1];
    bool act = c < CLS;
    float acc = 0.f;
    if (act) acc = bf2f(hws[(size_t)wv * CLS + c]);   // self-loop term
    int j = beg;
    for (; j + 8 <= endp; j += 8) {
        int s0 = csr[j],     s1 = csr[j + 1], s2 = csr[j + 2], s3 = csr[j + 3];
        int s4 = csr[j + 4], s5 = csr[j + 5], s6 = csr[j + 6], s7 = csr[j + 7];
        if (act) {
            float v0 = bf2f(hws[(size_t)s0 * CLS + c]);
            float v1 = bf2f(hws[(size_t)s1 * CLS + c]);
            float v2 = bf2f(hws[(size_t)s2 * CLS + c]);
            float v3 = bf2f(hws[(size_t)s3 * CLS + c]);
            float v4 = bf2f(hws[(size_t)s4 * CLS + c]);
            float v5 = bf2f(hws[(size_t)s5 * CLS + c]);
            float v6 = bf2f(hws[(size_t)s6 * CLS + c]);
            float v7 = bf2f(hws[(size_t)s7 * CLS + c]);
            acc += ((v0 + v1) + (v2 + v3)) + ((v4 + v5) + (v6 + v7));
        }
    }
    for (; j < endp; ++j) {
        int s = csr[j];
        if (act) acc += bf2f(hws[(size_t)s * CLS + c]);
    }
    float raw = 0.f;
    if (act) raw = acc * dinv[wv] + b2[c];
    float m = act ? raw : -3.0e38f;
    #pragma unroll
    for (int o = 32; o > 0; o >>= 1) m = fmaxf(m, __shfl_xor(m, o));
    float ex = act ? __expf(raw - m) : 0.f;
    float ssum = ex;
    #pragma unroll
    for (int o = 32; o > 0; o >>= 1) ssum += __shfl_xor(ssum, o);
    float sq = act ? raw * raw : 0.f;
    #pragma unroll
    for (int o = 32; o > 0; o >>= 1) sq += __shfl_xor(sq, o);
    size_t base = (size_t)wv * CLS + c;
    if (act) {
        xout[base]  = raw;
        float lse = m + __logf(ssum);
        lsm[base]   = raw - lse;
        sm[base]    = ex / ssum;
        xoutb[base] = f2bf(raw);
    }
    if (c == 0) rnorm[wv] = 1.0f / fmaxf(sqrtf(sq), EPS);
}

// ------------- per-edge cosine dissimilarity + gnn_edge ---------------------
// 80B row = 5 x uint4 loads per operand (full 40 bf16 channels)
__global__ void edge_kernel(const uint_t* __restrict__ pair,
                            const float* __restrict__ ew, const ushort_t* __restrict__ xoutb,
                            const float* __restrict__ rnorm,
                            float* __restrict__ cos_out, float* __restrict__ gnn_out, int E) {
    int e = blockIdx.x * blockDim.x + threadIdx.x;
    if (e >= E) return;
    uint_t u = pair[e];
    int s = (int)(u & 0xffffu);
    int d = (int)(u >> 16);
    const uint4* a4 = (const uint4*)(xoutb + (size_t)s * CLS);   // rows are 80B = 5*16B
    const uint4* b4 = (const uint4*)(xoutb + (size_t)d * CLS);
    uint4 a0 = a4[0], a1 = a4[1], a2 = a4[2], a3 = a4[3], a4v = a4[4];
    uint4 b0 = b4[0], b1 = b4[1], b2 = b4[2], b3 = b4[3], b4v = b4[4];
    float rs = rnorm[s], rd = rnorm[d];
    float dot = dot_u4(a0, b0) + dot_u4(a1, b1) + dot_u4(a2, b2)
              + dot_u4(a3, b3) + dot_u4(a4v, b4v);
    cos_out[e] = 1.0f - dot * rs * rd;
    gnn_out[e] = (ew[e] > 0.5f) ? 1.0f : -1.0f;
}

// ---------------------------------------------------------------------------
extern "C" void kernel_launch(void* const* d_in, const int* in_sizes, int n_in,
                              void* d_out, int out_size, void* d_ws, size_t ws_size,
                              hipStream_t stream) {
    const float* x   = (const float*)d_in[0];
    const void*  ei  = d_in[1];
    const float* ew  = (const float*)d_in[2];
    const float* W1  = (const float*)d_in[3];
    const float* b1  = (const float*)d_in[4];
    const float* W2  = (const float*)d_in[5];
    const float* b2  = (const float*)d_in[6];

    const int n = in_sizes[0] / F_IN;        // 50000
    const int E = in_sizes[2];               // 1600000

    // output segments (return order)
    float* lsm  = (float*)d_out;                                   // [n*CLS]
    float* xout = lsm + (size_t)n * CLS;                           // [n*CLS]
    float* cosO = xout + (size_t)n * CLS;                          // [E]
    float* gnnO = cosO + E;                                        // [E]
    float* smO  = gnnO + E;                                        // [n*CLS]

    // workspace layout (256B aligned)
    char* w = (char*)d_ws;
    auto alloc = [&](size_t bytes) {
        char* p = w;
        w += (bytes + 255) & ~(size_t)255;
        return p;
    };
    uint_t*   pair   = (uint_t*)  alloc((size_t)E * 4);
    ushort_t* csr16  = (ushort_t*)alloc((size_t)E * 2);
    ushort_t* rank16 = (ushort_t*)alloc((size_t)E * 2);
    int*      deg    = (int*)     alloc((size_t)n * 4);
    int*      rowptr = (int*)     alloc(((size_t)n + 1) * 4);
    float*    dinv   = (float*)   alloc((size_t)n * 4);
    ushort_t* xws    = (ushort_t*)alloc((size_t)n * HID * 2);
    ushort_t* hws    = (ushort_t*)alloc((size_t)n * CLS * 2);
    ushort_t* xoutb  = (ushort_t*)alloc((size_t)n * CLS * 2);
    float*    rnorm  = (float*)   alloc((size_t)n * 4);
    ushort_t* W1s    = (ushort_t*)alloc((size_t)4 * 8 * 64 * 8 * 2);   // 32 KB
    int*      bsum   = (int*)     alloc(256 * 4);
    int*      flag   = (int*)     alloc(64);

    const int nscan = (n + 255) / 256;       // 196 scan blocks (<= 256)

    detect_kernel<<<1, 64, 0, stream>>>((const int*)ei, flag);
    convert_w1_kernel<<<8, 256, 0, stream>>>(W1, W1s);
    init_deg_kernel<<<(n + 255) / 256, 256, 0, stream>>>(deg, n);
    convert_kernel<<<(E + 255) / 256, 256, 0, stream>>>(ei, flag, pair, deg, rank16, E);
    scan1_kernel<<<nscan, 256, 0, stream>>>(deg, rowptr, bsum, dinv, n);
    scan2_kernel<<<1, 256, 0, stream>>>(bsum, nscan);
    scan3_kernel<<<nscan, 256, 0, stream>>>(rowptr, bsum, n, E);
    place_kernel<<<(E + 255) / 256, 256, 0, stream>>>(pair, rank16, rowptr, csr16, E);
    gemm1_mfma_kernel<<<(n + 15) / 16, 256, 0, stream>>>(x, W1s, dinv, xws, n);
    gather1_gemm2_kernel<<<((size_t)n * 64 + 255) / 256, 256, 0, stream>>>(rowptr, csr16, xws, dinv,
                                                                           b1, W2, hws, n);
    gather2_fin_kernel<<<((size_t)n * 64 + 255) / 256, 256, 0, stream>>>(rowptr, csr16, hws, dinv, b2,
                                                                         xout, lsm, smO, xoutb, rnorm, n);
    edge_kernel<<<(E + 255) / 256, 256, 0, stream>>>(pair, ew, xoutb, rnorm, cosO, gnnO, E);
}